// Round 15
// baseline (166.241 us; speedup 1.0000x reference)
//
#include <hip/hip_runtime.h>

#define SEQ 4096
#define DMODEL 1024
#define HEADS 16
#define HD 64
#define NQKV 3072

typedef __attribute__((ext_vector_type(8))) __bf16 bf16x8;
typedef __attribute__((ext_vector_type(4))) __bf16 bf16x4;
typedef __attribute__((ext_vector_type(8))) short short8;
typedef __attribute__((ext_vector_type(4))) float f32x4;

__device__ __forceinline__ unsigned short f2bf(float f) {
    unsigned u = __builtin_bit_cast(unsigned, f);
    return (unsigned short)((u + 0x7fffu + ((u >> 16) & 1u)) >> 16);
}
__device__ __forceinline__ float bf2f(unsigned short h) {
    return __builtin_bit_cast(float, (unsigned)h << 16);
}

__device__ __forceinline__ void gload16(const void* g, void* l) {
    __builtin_amdgcn_global_load_lds(
        (const __attribute__((address_space(1))) unsigned int*)g,
        (__attribute__((address_space(3))) unsigned int*)l, 16, 0, 0);
}

// ---------------- fp32 -> bf16 convert, all three tensors in one launch ----------------
__global__ void f2bf_all(const float* __restrict__ x, const float* __restrict__ wqkv,
                         const float* __restrict__ wo, unsigned short* __restrict__ dst) {
    const int N0 = SEQ * DMODEL / 4;
    const int N1 = N0 + NQKV * DMODEL / 4;
    const int NT = N1 + DMODEL * DMODEL / 4;
    int i = blockIdx.x * 256 + threadIdx.x;
    int stride = gridDim.x * 256;
    for (; i < NT; i += stride) {
        const float4* src;
        if (i < N0)      src = reinterpret_cast<const float4*>(x) + i;
        else if (i < N1) src = reinterpret_cast<const float4*>(wqkv) + (i - N0);
        else             src = reinterpret_cast<const float4*>(wo) + (i - N1);
        float4 f = *src;
        ushort4 o;
        o.x = f2bf(f.x); o.y = f2bf(f.y); o.z = f2bf(f.z); o.w = f2bf(f.w);
        reinterpret_cast<ushort4*>(dst)[i] = o;
    }
}

// ---------------- bf16 GEMM, C = A(MxK) * B(NxK)^T ----------------
template <int EPI>
__global__ __launch_bounds__(256) void gemm_bt(const unsigned short* __restrict__ A,
                                               const unsigned short* __restrict__ B,
                                               float* __restrict__ outF,
                                               unsigned short* __restrict__ outB,
                                               int M, int N, int K) {
    alignas(16) __shared__ unsigned short a_lds[2][128 * 32];
    alignas(16) __shared__ unsigned short b_lds[2][128 * 32];
    const int tid = threadIdx.x;
    const int wave = tid >> 6, lane = tid & 63;
    const int l16 = lane & 15, g = lane >> 4;
    const int wr = wave >> 1, wc = wave & 1;
    const int bm = blockIdx.x, bn = blockIdx.y;

    const int lrow = lane >> 2;
    const int lcol = (lane & 3) * 8;

    const unsigned short* Ag = A + (size_t)(bm * 128 + lrow) * K + lcol;
    const unsigned short* Bg = B + (size_t)(bn * 128 + lrow) * K + lcol;

    f32x4 acc[4][4] = {};
    const int NS = K / 32;

    auto STAGE = [&](int b, int ks) {
#pragma unroll
        for (int j = 0; j < 2; ++j) {
            int chunk = wave * 2 + j;
            gload16(Ag + (size_t)(chunk * 16) * K + ks * 32, a_lds[b] + chunk * 512);
            gload16(Bg + (size_t)(chunk * 16) * K + ks * 32, b_lds[b] + chunk * 512);
        }
    };

    STAGE(0, 0);

    for (int ks = 0; ks < NS; ++ks) {
        const int cur = ks & 1;
        asm volatile("s_waitcnt vmcnt(0)" ::: "memory");
        __builtin_amdgcn_s_barrier();
        if (ks + 1 < NS) STAGE(cur ^ 1, ks + 1);

        bf16x8 af[4], bfr[4];
#pragma unroll
        for (int m = 0; m < 4; ++m)
            af[m] = *reinterpret_cast<const bf16x8*>(a_lds[cur] + (wr * 64 + m * 16 + l16) * 32 + g * 8);
#pragma unroll
        for (int n = 0; n < 4; ++n)
            bfr[n] = *reinterpret_cast<const bf16x8*>(b_lds[cur] + (wc * 64 + n * 16 + l16) * 32 + g * 8);
        __builtin_amdgcn_s_setprio(1);
#pragma unroll
        for (int m = 0; m < 4; ++m)
#pragma unroll
            for (int n = 0; n < 4; ++n)
                acc[m][n] = __builtin_amdgcn_mfma_f32_16x16x32_bf16(af[m], bfr[n], acc[m][n], 0, 0, 0);
        __builtin_amdgcn_s_setprio(0);
    }

#pragma unroll
    for (int m = 0; m < 4; ++m)
#pragma unroll
        for (int n = 0; n < 4; ++n)
#pragma unroll
            for (int r = 0; r < 4; ++r) {
                int row = bm * 128 + wr * 64 + m * 16 + g * 4 + r;
                int col = bn * 128 + wc * 64 + n * 16 + l16;
                float v = acc[m][n][r];
                if (EPI == 0) {
                    int part = col >> 10;
                    int hd = col & 1023;
                    int h = hd >> 6, d = hd & 63;
                    outB[(size_t)((part * HEADS + h) * SEQ + row) * HD + d] = f2bf(v);
                } else {
                    outF[(size_t)row * N + col] = v;
                }
            }
}

// ---------------- RoPE in place on Q,K (Q scaled by 1/8 * log2e) ----------------
__global__ __launch_bounds__(256) void rope_kernel(unsigned short* qkv, const int* __restrict__ pos) {
    int idx = blockIdx.x * 256 + threadIdx.x;
    int chunk = idx & 7;
    int row = idx >> 3;
    int s = row & (SEQ - 1);
    int ph = row >> 12;
    float p = (float)pos[s];
    float scale = (ph < HEADS) ? 0.125f * 1.4426950408889634f : 1.0f;
    unsigned short* base = qkv + ((size_t)ph * SEQ + s) * HD + chunk * 8;
    short8 v = *reinterpret_cast<short8*>(base);
    short8 o;
    const float k = -13.287712379549449f / 32.0f;
#pragma unroll
    for (int j = 0; j < 4; ++j) {
        int i = chunk * 4 + j;
        float ang = p * exp2f((float)i * k);
        float sn, cs;
        sincosf(ang, &sn, &cs);
        float x1 = bf2f((unsigned short)v[2 * j]);
        float x2 = bf2f((unsigned short)v[2 * j + 1]);
        o[2 * j]     = (short)f2bf((x1 * cs - x2 * sn) * scale);
        o[2 * j + 1] = (short)f2bf((x1 * sn + x2 * cs) * scale);
    }
    *reinterpret_cast<short8*>(base) = o;
}

// ---------------- V transpose: [s][d] -> VT [h][d][s] ----------------
__global__ __launch_bounds__(256) void transpose_v(const unsigned short* __restrict__ qkv,
                                                   unsigned short* __restrict__ vt) {
    const int st = blockIdx.x;
    const int h = blockIdx.y;
    __shared__ unsigned short tile[64][72];
    const unsigned short* Vg = qkv + (size_t)((2 * HEADS + h) * SEQ) * HD;
    const int tid = threadIdx.x;
#pragma unroll
    for (int j = 0; j < 2; ++j) {
        int b = (tid + j * 256) * 8;
        int row = b >> 6;
        int col = b & 63;
        short8 v = *reinterpret_cast<const short8*>(Vg + (size_t)(st * 64 + row) * HD + col);
#pragma unroll
        for (int i = 0; i < 8; ++i) tile[row][col + i] = (unsigned short)v[i];
    }
    __syncthreads();
#pragma unroll
    for (int j = 0; j < 2; ++j) {
        int b = (tid + j * 256) * 8;
        int d = b >> 6;
        int sc = b & 63;
        short8 o;
#pragma unroll
        for (int i = 0; i < 8; ++i) o[i] = (short)tile[sc + i][d];
        *reinterpret_cast<short8*>(vt + (size_t)(h * HD + d) * SEQ + st * 64 + sc) = o;
    }
}

// ---------------- causal flash attention, task-queue + split-K ----------------
// R14 per-wave compute (QBLK=128, KVBLK=128, 8 waves, 2-buffer prefetch, swizzled
// K/V halves). Work = 108 tasks/XCD pulled from per-XCD atomic queue, LPT order:
// qtiles 10..31 split into two K-half tasks (partials -> merge), 0..9 unsplit.
__global__ __launch_bounds__(512) void attn_kernel(const unsigned short* __restrict__ qkv,
                                                   const unsigned short* __restrict__ vt,
                                                   unsigned short* __restrict__ attnout,
                                                   int* __restrict__ qcnt,
                                                   unsigned short* __restrict__ pO,
                                                   float* __restrict__ lmf) {
    const int xcd = blockIdx.x & 7;
    const int tid = threadIdx.x;
    const int wave = tid >> 6, lane = tid & 63;
    const int l16 = lane & 15, g = lane >> 4;

    alignas(16) __shared__ unsigned short k_lds[2][128 * 64];   // [kv][d], 128B rows
    alignas(16) __shared__ unsigned short v_lds[2][2][64 * 64]; // [h64][d][kv'], 128B rows
    alignas(16) __shared__ unsigned short p_lds[8][16 * 64];    // per-wave [q][kv-half]
    __shared__ int slot_sh;

    char* pwave = (char*)p_lds + wave * 2048;
    const int rsw = (l16 & 7) << 4;

    for (;;) {
        if (tid == 0) slot_sh = atomicAdd(&qcnt[xcd], 1);
        __syncthreads();
        const int t = slot_sh;
        __syncthreads();
        if (t >= 108) break;

        int qtile, hloc, khalf, k0, k1;
        bool isSplit;
        if (t < 88) {                       // split tasks, LPT (qtile 31..10)
            qtile = 31 - (t >> 2);
            hloc = (t >> 1) & 1;
            khalf = t & 1;
            int T = qtile + 1, H = (T + 1) >> 1;
            k0 = khalf ? H : 0;
            k1 = khalf ? T : H;
            isSplit = true;
        } else {                            // unsplit short tasks (qtile 9..0)
            int rem = t - 88;
            qtile = 9 - (rem >> 1);
            hloc = rem & 1;
            khalf = 0;
            k0 = 0; k1 = qtile + 1;
            isSplit = false;
        }
        const int h = xcd * 2 + hloc;

        const unsigned short* Qg = qkv + (size_t)((0 * HEADS + h) * SEQ) * HD;
        const unsigned short* Kg = qkv + (size_t)((1 * HEADS + h) * SEQ) * HD;
        const unsigned short* VTg = vt + (size_t)h * HD * SEQ;

        const int qbase = qtile * 128 + wave * 16;
        bf16x8 qf[2];
        qf[0] = *reinterpret_cast<const bf16x8*>(Qg + (size_t)(qbase + l16) * HD + g * 8);
        qf[1] = *reinterpret_cast<const bf16x8*>(Qg + (size_t)(qbase + l16) * HD + 32 + g * 8);

        bf16x8 ones;
#pragma unroll
        for (int j2 = 0; j2 < 8; ++j2) ones[j2] = (__bf16)1.0f;

        f32x4 o_acc[4] = {};
        f32x4 l_acc = {};
        float m_r = -1e30f;

        auto STAGE = [&](int b, int kt) {
#pragma unroll
            for (int i = 0; i < 2; ++i) {
                int base = wave * 2048 + i * 1024;
                int byte = base + lane * 16;
                int krow = byte >> 7;
                int kc8 = ((byte >> 4) & 7) ^ (krow & 7);
                gload16(Kg + (size_t)(kt * 128 + krow) * HD + kc8 * 8, (char*)k_lds[b] + base);
                int fr = byte >> 7;
                int h64 = fr >> 6, vd = fr & 63;
                int vc8 = ((byte >> 4) & 7) ^ (vd & 7);
                gload16(VTg + (size_t)vd * SEQ + kt * 128 + h64 * 64 + vc8 * 8,
                        (char*)v_lds[b] + base);
            }
        };

        STAGE(0, k0);

        for (int kt = k0; kt < k1; ++kt) {
            const int cur = (kt - k0) & 1;
            asm volatile("s_waitcnt vmcnt(0)" ::: "memory");
            __builtin_amdgcn_s_barrier();
            if (kt + 1 < k1) STAGE(cur ^ 1, kt + 1);

            const bool doB = (kt * 128 + 64) <= (qbase + 15);

            f32x4 s[8] = {};
            __builtin_amdgcn_s_setprio(1);
#pragma unroll
            for (int nt = 0; nt < 4; ++nt) {
                int row = nt * 16 + l16;
#pragma unroll
                for (int kk = 0; kk < 2; ++kk) {
                    bf16x8 kf = *reinterpret_cast<const bf16x8*>(
                        (char*)k_lds[cur] + row * 128 + (((kk * 4 + g) << 4) ^ rsw));
                    s[nt] = __builtin_amdgcn_mfma_f32_16x16x32_bf16(kf, qf[kk], s[nt], 0, 0, 0);
                }
            }
            if (doB) {
#pragma unroll
                for (int nt = 0; nt < 4; ++nt) {
                    int row = 64 + nt * 16 + l16;
#pragma unroll
                    for (int kk = 0; kk < 2; ++kk) {
                        bf16x8 kf = *reinterpret_cast<const bf16x8*>(
                            (char*)k_lds[cur] + row * 128 + (((kk * 4 + g) << 4) ^ rsw));
                        s[4 + nt] = __builtin_amdgcn_mfma_f32_16x16x32_bf16(kf, qf[kk], s[4 + nt], 0, 0, 0);
                    }
                }
            }
            __builtin_amdgcn_s_setprio(0);

            if (kt * 128 + 127 > qbase) {
                int qrow = qbase + l16;
#pragma unroll
                for (int nt = 0; nt < 4; ++nt)
#pragma unroll
                    for (int r = 0; r < 4; ++r) {
                        int kv = kt * 128 + nt * 16 + g * 4 + r;
                        if (kv > qrow) s[nt][r] = -1e30f;
                        if (kv + 64 > qrow) s[4 + nt][r] = -1e30f;
                    }
            }

            f32x4 m4;
#pragma unroll
            for (int r = 0; r < 4; ++r) {
                float a = fmaxf(fmaxf(s[0][r], s[1][r]), fmaxf(s[2][r], s[3][r]));
                float b = fmaxf(fmaxf(s[4][r], s[5][r]), fmaxf(s[6][r], s[7][r]));
                m4[r] = fmaxf(a, b);
            }
            float mx = fmaxf(fmaxf(m4[0], m4[1]), fmaxf(m4[2], m4[3]));
            mx = fmaxf(mx, __shfl_xor(mx, 16));
            mx = fmaxf(mx, __shfl_xor(mx, 32));

            if (__any(mx > m_r + 8.0f)) {
                float mnew = fmaxf(m_r, mx);
                float alpha = __builtin_amdgcn_exp2f(m_r - mnew);
                m_r = mnew;
#pragma unroll
                for (int dt = 0; dt < 4; ++dt)
#pragma unroll
                    for (int r = 0; r < 4; ++r) o_acc[dt][r] *= alpha;
                l_acc[0] *= alpha;
            }

#pragma unroll
            for (int i = 0; i < 8; ++i)
#pragma unroll
                for (int r = 0; r < 4; ++r) s[i][r] = __builtin_amdgcn_exp2f(s[i][r] - m_r);

            __builtin_amdgcn_s_setprio(1);
#pragma unroll
            for (int h64 = 0; h64 < 2; ++h64) {
                if (h64 && !doB) break;
#pragma unroll
                for (int nt = 0; nt < 4; ++nt) {
                    bf16x4 pb;
#pragma unroll
                    for (int r = 0; r < 4; ++r) pb[r] = (__bf16)s[h64 * 4 + nt][r];
                    *reinterpret_cast<bf16x4*>(pwave + l16 * 128 + ((nt * 32 + g * 8) ^ rsw)) = pb;
                }
                bf16x8 pfrag[2];
#pragma unroll
                for (int kk = 0; kk < 2; ++kk)
                    pfrag[kk] = *reinterpret_cast<const bf16x8*>(
                        pwave + l16 * 128 + (((kk * 4 + g) << 4) ^ rsw));

#pragma unroll
                for (int dt = 0; dt < 4; ++dt) {
                    int row = dt * 16 + l16;
#pragma unroll
                    for (int kk = 0; kk < 2; ++kk) {
                        bf16x8 vf = *reinterpret_cast<const bf16x8*>(
                            (char*)v_lds[cur][h64] + row * 128 + (((kk * 4 + g) << 4) ^ rsw));
                        o_acc[dt] = __builtin_amdgcn_mfma_f32_16x16x32_bf16(vf, pfrag[kk], o_acc[dt], 0, 0, 0);
                    }
                }
                l_acc = __builtin_amdgcn_mfma_f32_16x16x32_bf16(ones, pfrag[0], l_acc, 0, 0, 0);
                l_acc = __builtin_amdgcn_mfma_f32_16x16x32_bf16(ones, pfrag[1], l_acc, 0, 0, 0);
            }
            __builtin_amdgcn_s_setprio(0);
        }

        const int ql = wave * 16 + l16;
        if (isSplit) {
            // store unnormalized partial: O (bf16), l & m (f32)
            int sidx = (h * 22 + (qtile - 10)) * 2 + khalf;
            unsigned short* Op = pO + (size_t)sidx * 8192;
#pragma unroll
            for (int dt = 0; dt < 4; ++dt) {
                ushort4 ov;
                ov.x = f2bf(o_acc[dt][0]);
                ov.y = f2bf(o_acc[dt][1]);
                ov.z = f2bf(o_acc[dt][2]);
                ov.w = f2bf(o_acc[dt][3]);
                *reinterpret_cast<ushort4*>(Op + ql * 64 + dt * 16 + g * 4) = ov;
            }
            if (g == 0) {
                lmf[sidx * 256 + ql] = l_acc[0];
                lmf[sidx * 256 + 128 + ql] = m_r;
            }
        } else {
            float inv = 1.0f / l_acc[0];
            int q = qtile * 128 + ql;
#pragma unroll
            for (int dt = 0; dt < 4; ++dt) {
                ushort4 ov;
                ov.x = f2bf(o_acc[dt][0] * inv);
                ov.y = f2bf(o_acc[dt][1] * inv);
                ov.z = f2bf(o_acc[dt][2] * inv);
                ov.w = f2bf(o_acc[dt][3] * inv);
                *reinterpret_cast<ushort4*>(attnout + (size_t)q * DMODEL + h * HD + dt * 16 + g * 4) = ov;
            }
        }
    }
}

// ---------------- merge K-half partials ----------------
__global__ __launch_bounds__(256) void merge_kernel(const unsigned short* __restrict__ pO,
                                                    const float* __restrict__ lmf,
                                                    unsigned short* __restrict__ attnout) {
    int idx = blockIdx.x * 256 + threadIdx.x;   // 16 h x 22 qt x 128 q x 8 d8
    if (idx >= 16 * 22 * 1024) return;
    int h = idx / (22 * 1024);
    int r = idx % (22 * 1024);
    int qt = r >> 10;
    int rr = r & 1023;
    int q = rr >> 3, d8 = rr & 7;

    int s0 = (h * 22 + qt) * 2;
    float l0 = lmf[s0 * 256 + q],       m0 = lmf[s0 * 256 + 128 + q];
    float l1 = lmf[(s0 + 1) * 256 + q], m1 = lmf[(s0 + 1) * 256 + 128 + q];
    float m = fmaxf(m0, m1);
    float a0 = __builtin_amdgcn_exp2f(m0 - m), a1 = __builtin_amdgcn_exp2f(m1 - m);
    float L = l0 * a0 + l1 * a1;
    float c0 = a0 / L, c1 = a1 / L;

    const unsigned short* O0 = pO + (size_t)s0 * 8192 + q * 64 + d8 * 8;
    const unsigned short* O1 = O0 + 8192;
    short8 v0 = *reinterpret_cast<const short8*>(O0);
    short8 v1 = *reinterpret_cast<const short8*>(O1);
    short8 o;
#pragma unroll
    for (int j = 0; j < 8; ++j) {
        float val = bf2f((unsigned short)v0[j]) * c0 + bf2f((unsigned short)v1[j]) * c1;
        o[j] = (short)f2bf(val);
    }
    int qtile = qt + 10;
    *reinterpret_cast<short8*>(attnout + (size_t)(qtile * 128 + q) * DMODEL + h * HD + d8 * 8) = o;
}

extern "C" void kernel_launch(void* const* d_in, const int* in_sizes, int n_in,
                              void* d_out, int out_size, void* d_ws, size_t ws_size,
                              hipStream_t stream) {
    const float* x = (const float*)d_in[0];
    const int* pos = (const int*)d_in[1];
    const float* wqkv = (const float*)d_in[2];
    const float* wo = (const float*)d_in[3];
    float* out = (float*)d_out;

    unsigned short* xb = (unsigned short*)d_ws;
    unsigned short* wqkvb = xb + (size_t)SEQ * DMODEL;
    unsigned short* wob = wqkvb + (size_t)NQKV * DMODEL;
    unsigned short* qkvp = wob + (size_t)DMODEL * DMODEL;
    unsigned short* vt = qkvp + (size_t)3 * HEADS * SEQ * HD;
    unsigned short* attnb = vt + (size_t)HEADS * HD * SEQ;

    // scratch for the queue + split-K partials lives in xb/wqkvb (dead after gemm1)
    char* sbase = (char*)d_ws;
    int* qcnt = (int*)sbase;                                   // 8 ints
    float* lmf = (float*)(sbase + 256);                        // 704*256 f32 = 720 KB
    unsigned short* pO = (unsigned short*)(sbase + 256 + (1 << 20));  // 704*16KB = 11.5 MB

    f2bf_all<<<2048, 256, 0, stream>>>(x, wqkv, wo, xb);

    dim3 g1(SEQ / 128, NQKV / 128);
    gemm_bt<0><<<g1, 256, 0, stream>>>(xb, wqkvb, nullptr, qkvp, SEQ, NQKV, DMODEL);

    rope_kernel<<<(2 * HEADS * SEQ * 8) / 256, 256, 0, stream>>>(qkvp, pos);
    transpose_v<<<dim3(SEQ / 64, HEADS), 256, 0, stream>>>(qkvp, vt);

    hipMemsetAsync(qcnt, 0, 64, stream);
    attn_kernel<<<512, 512, 0, stream>>>(qkvp, vt, attnb, qcnt, pO, lmf);
    merge_kernel<<<(16 * 22 * 1024 + 255) / 256, 256, 0, stream>>>(pO, lmf, attnb);

    dim3 g2(SEQ / 128, DMODEL / 128);
    gemm_bt<1><<<g2, 256, 0, stream>>>(attnb, wob, out, nullptr, SEQ, DMODEL, DMODEL);
}

// Round 16
// 148.606 us; speedup vs baseline: 1.1187x; 1.1187x over previous
//
#include <hip/hip_runtime.h>

#define SEQ 4096
#define DMODEL 1024
#define HEADS 16
#define HD 64
#define NQKV 3072

typedef __attribute__((ext_vector_type(8))) __bf16 bf16x8;
typedef __attribute__((ext_vector_type(4))) __bf16 bf16x4;
typedef __attribute__((ext_vector_type(8))) short short8;
typedef __attribute__((ext_vector_type(4))) float f32x4;

__device__ __forceinline__ unsigned short f2bf(float f) {
    unsigned u = __builtin_bit_cast(unsigned, f);
    return (unsigned short)((u + 0x7fffu + ((u >> 16) & 1u)) >> 16);
}
__device__ __forceinline__ float bf2f(unsigned short h) {
    return __builtin_bit_cast(float, (unsigned)h << 16);
}

__device__ __forceinline__ void gload16(const void* g, void* l) {
    __builtin_amdgcn_global_load_lds(
        (const __attribute__((address_space(1))) unsigned int*)g,
        (__attribute__((address_space(3))) unsigned int*)l, 16, 0, 0);
}

// task table per head, LPT (length-descending). bit6=split, bit5=khalf, bits0-4=qtile
#define TS(qt, kh) (0x40 | ((kh) << 5) | (qt))
__device__ __constant__ unsigned char TASKS[48] = {
    TS(31,0), TS(31,1), TS(30,0), 15,                       // len 16
    TS(30,1), TS(29,0), TS(29,1), TS(28,0), 14,             // len 15
    TS(28,1), TS(27,0), TS(27,1), TS(26,0), 13,             // len 14
    TS(26,1), TS(25,0), TS(25,1), TS(24,0), 12,             // len 13
    TS(24,1), TS(23,0), TS(23,1), TS(22,0), 11,             // len 12
    TS(22,1), TS(21,0), TS(21,1), TS(20,0), 10,             // len 11
    TS(20,1), TS(19,0), TS(19,1), TS(18,0), 9,              // len 10
    TS(18,1), TS(17,0), TS(17,1), TS(16,0), 8,              // len 9
    TS(16,1), 7,                                            // len 8
    6, 5, 4, 3, 2, 1, 0                                     // len 7..1
};

// ---------------- fp32 -> bf16 convert, all three tensors in one launch ----------------
__global__ void f2bf_all(const float* __restrict__ x, const float* __restrict__ wqkv,
                         const float* __restrict__ wo, unsigned short* __restrict__ dst) {
    const int N0 = SEQ * DMODEL / 4;
    const int N1 = N0 + NQKV * DMODEL / 4;
    const int NT = N1 + DMODEL * DMODEL / 4;
    int i = blockIdx.x * 256 + threadIdx.x;
    int stride = gridDim.x * 256;
    for (; i < NT; i += stride) {
        const float4* src;
        if (i < N0)      src = reinterpret_cast<const float4*>(x) + i;
        else if (i < N1) src = reinterpret_cast<const float4*>(wqkv) + (i - N0);
        else             src = reinterpret_cast<const float4*>(wo) + (i - N1);
        float4 f = *src;
        ushort4 o;
        o.x = f2bf(f.x); o.y = f2bf(f.y); o.z = f2bf(f.z); o.w = f2bf(f.w);
        reinterpret_cast<ushort4*>(dst)[i] = o;
    }
}

// ---------------- bf16 GEMM, C = A(MxK) * B(NxK)^T ----------------
template <int EPI>
__global__ __launch_bounds__(256) void gemm_bt(const unsigned short* __restrict__ A,
                                               const unsigned short* __restrict__ B,
                                               float* __restrict__ outF,
                                               unsigned short* __restrict__ outB,
                                               int M, int N, int K) {
    alignas(16) __shared__ unsigned short a_lds[2][128 * 32];
    alignas(16) __shared__ unsigned short b_lds[2][128 * 32];
    const int tid = threadIdx.x;
    const int wave = tid >> 6, lane = tid & 63;
    const int l16 = lane & 15, g = lane >> 4;
    const int wr = wave >> 1, wc = wave & 1;
    const int bm = blockIdx.x, bn = blockIdx.y;

    const int lrow = lane >> 2;
    const int lcol = (lane & 3) * 8;

    const unsigned short* Ag = A + (size_t)(bm * 128 + lrow) * K + lcol;
    const unsigned short* Bg = B + (size_t)(bn * 128 + lrow) * K + lcol;

    f32x4 acc[4][4] = {};
    const int NS = K / 32;

    auto STAGE = [&](int b, int ks) {
#pragma unroll
        for (int j = 0; j < 2; ++j) {
            int chunk = wave * 2 + j;
            gload16(Ag + (size_t)(chunk * 16) * K + ks * 32, a_lds[b] + chunk * 512);
            gload16(Bg + (size_t)(chunk * 16) * K + ks * 32, b_lds[b] + chunk * 512);
        }
    };

    STAGE(0, 0);

    for (int ks = 0; ks < NS; ++ks) {
        const int cur = ks & 1;
        asm volatile("s_waitcnt vmcnt(0)" ::: "memory");
        __builtin_amdgcn_s_barrier();
        if (ks + 1 < NS) STAGE(cur ^ 1, ks + 1);

        bf16x8 af[4], bfr[4];
#pragma unroll
        for (int m = 0; m < 4; ++m)
            af[m] = *reinterpret_cast<const bf16x8*>(a_lds[cur] + (wr * 64 + m * 16 + l16) * 32 + g * 8);
#pragma unroll
        for (int n = 0; n < 4; ++n)
            bfr[n] = *reinterpret_cast<const bf16x8*>(b_lds[cur] + (wc * 64 + n * 16 + l16) * 32 + g * 8);
        __builtin_amdgcn_s_setprio(1);
#pragma unroll
        for (int m = 0; m < 4; ++m)
#pragma unroll
            for (int n = 0; n < 4; ++n)
                acc[m][n] = __builtin_amdgcn_mfma_f32_16x16x32_bf16(af[m], bfr[n], acc[m][n], 0, 0, 0);
        __builtin_amdgcn_s_setprio(0);
    }

#pragma unroll
    for (int m = 0; m < 4; ++m)
#pragma unroll
        for (int n = 0; n < 4; ++n)
#pragma unroll
            for (int r = 0; r < 4; ++r) {
                int row = bm * 128 + wr * 64 + m * 16 + g * 4 + r;
                int col = bn * 128 + wc * 64 + n * 16 + l16;
                float v = acc[m][n][r];
                if (EPI == 0) {
                    int part = col >> 10;
                    int hd = col & 1023;
                    int h = hd >> 6, d = hd & 63;
                    outB[(size_t)((part * HEADS + h) * SEQ + row) * HD + d] = f2bf(v);
                } else {
                    outF[(size_t)row * N + col] = v;
                }
            }
}

// ---------------- RoPE in place on Q,K (Q scaled by 1/8 * log2e) ----------------
__global__ __launch_bounds__(256) void rope_kernel(unsigned short* qkv, const int* __restrict__ pos) {
    int idx = blockIdx.x * 256 + threadIdx.x;
    int chunk = idx & 7;
    int row = idx >> 3;
    int s = row & (SEQ - 1);
    int ph = row >> 12;
    float p = (float)pos[s];
    float scale = (ph < HEADS) ? 0.125f * 1.4426950408889634f : 1.0f;
    unsigned short* base = qkv + ((size_t)ph * SEQ + s) * HD + chunk * 8;
    short8 v = *reinterpret_cast<short8*>(base);
    short8 o;
    const float k = -13.287712379549449f / 32.0f;
#pragma unroll
    for (int j = 0; j < 4; ++j) {
        int i = chunk * 4 + j;
        float ang = p * exp2f((float)i * k);
        float sn, cs;
        sincosf(ang, &sn, &cs);
        float x1 = bf2f((unsigned short)v[2 * j]);
        float x2 = bf2f((unsigned short)v[2 * j + 1]);
        o[2 * j]     = (short)f2bf((x1 * cs - x2 * sn) * scale);
        o[2 * j + 1] = (short)f2bf((x1 * sn + x2 * cs) * scale);
    }
    *reinterpret_cast<short8*>(base) = o;
}

// ---------------- V transpose: [s][d] -> VT [h][d][s] ----------------
__global__ __launch_bounds__(256) void transpose_v(const unsigned short* __restrict__ qkv,
                                                   unsigned short* __restrict__ vt) {
    const int st = blockIdx.x;
    const int h = blockIdx.y;
    __shared__ unsigned short tile[64][72];
    const unsigned short* Vg = qkv + (size_t)((2 * HEADS + h) * SEQ) * HD;
    const int tid = threadIdx.x;
#pragma unroll
    for (int j = 0; j < 2; ++j) {
        int b = (tid + j * 256) * 8;
        int row = b >> 6;
        int col = b & 63;
        short8 v = *reinterpret_cast<const short8*>(Vg + (size_t)(st * 64 + row) * HD + col);
#pragma unroll
        for (int i = 0; i < 8; ++i) tile[row][col + i] = (unsigned short)v[i];
    }
    __syncthreads();
#pragma unroll
    for (int j = 0; j < 2; ++j) {
        int b = (tid + j * 256) * 8;
        int d = b >> 6;
        int sc = b & 63;
        short8 o;
#pragma unroll
        for (int i = 0; i < 8; ++i) o[i] = (short)tile[sc + i][d];
        *reinterpret_cast<short8*>(vt + (size_t)(h * HD + d) * SEQ + st * 64 + sc) = o;
    }
}

// ---------------- causal flash attention, static split-K LPT tasks ----------------
// R14 per-wave compute (QBLK=128, KVBLK=128, 8 waves, 2-buffer prefetch, swizzled
// K/V halves, 80KB LDS = 2 blocks/CU). One task per block: qtiles 16..31 split
// into two K-halves (partials -> merge), qtiles 0..15 unsplit. 96 tasks/XCD.
__global__ __launch_bounds__(512) void attn_kernel(const unsigned short* __restrict__ qkv,
                                                   const unsigned short* __restrict__ vt,
                                                   unsigned short* __restrict__ attnout,
                                                   unsigned short* __restrict__ pO,
                                                   float* __restrict__ lmf) {
    const int bid = blockIdx.x;
    const int xcd = bid & 7;
    const int slot = bid >> 3;                // 0..95
    const int hloc = slot & 1;
    const unsigned char e = TASKS[slot >> 1];
    const int qtile = e & 31;
    const int khalf = (e >> 5) & 1;
    const bool isSplit = (e >> 6) != 0;
    const int T = qtile + 1, Hh = (T + 1) >> 1;
    const int k0 = isSplit ? (khalf ? Hh : 0) : 0;
    const int k1 = isSplit ? (khalf ? T : Hh) : T;
    const int h = xcd * 2 + hloc;

    const int tid = threadIdx.x;
    const int wave = tid >> 6, lane = tid & 63;
    const int l16 = lane & 15, g = lane >> 4;

    alignas(16) __shared__ unsigned short k_lds[2][128 * 64];   // [kv][d], 128B rows
    alignas(16) __shared__ unsigned short v_lds[2][2][64 * 64]; // [h64][d][kv'], 128B rows
    alignas(16) __shared__ unsigned short p_lds[8][16 * 64];    // per-wave [q][kv-half]

    const unsigned short* Qg = qkv + (size_t)((0 * HEADS + h) * SEQ) * HD;
    const unsigned short* Kg = qkv + (size_t)((1 * HEADS + h) * SEQ) * HD;
    const unsigned short* VTg = vt + (size_t)h * HD * SEQ;

    const int qbase = qtile * 128 + wave * 16;
    bf16x8 qf[2];
    qf[0] = *reinterpret_cast<const bf16x8*>(Qg + (size_t)(qbase + l16) * HD + g * 8);
    qf[1] = *reinterpret_cast<const bf16x8*>(Qg + (size_t)(qbase + l16) * HD + 32 + g * 8);

    bf16x8 ones;
#pragma unroll
    for (int j2 = 0; j2 < 8; ++j2) ones[j2] = (__bf16)1.0f;

    f32x4 o_acc[4] = {};
    f32x4 l_acc = {};
    float m_r = -1e30f;

    char* pwave = (char*)p_lds + wave * 2048;
    const int rsw = (l16 & 7) << 4;

    auto STAGE = [&](int b, int kt) {
#pragma unroll
        for (int i = 0; i < 2; ++i) {
            int base = wave * 2048 + i * 1024;
            int byte = base + lane * 16;
            int krow = byte >> 7;
            int kc8 = ((byte >> 4) & 7) ^ (krow & 7);
            gload16(Kg + (size_t)(kt * 128 + krow) * HD + kc8 * 8, (char*)k_lds[b] + base);
            int fr = byte >> 7;
            int h64 = fr >> 6, vd = fr & 63;
            int vc8 = ((byte >> 4) & 7) ^ (vd & 7);
            gload16(VTg + (size_t)vd * SEQ + kt * 128 + h64 * 64 + vc8 * 8,
                    (char*)v_lds[b] + base);
        }
    };

    STAGE(0, k0);

    for (int kt = k0; kt < k1; ++kt) {
        const int cur = (kt - k0) & 1;
        asm volatile("s_waitcnt vmcnt(0)" ::: "memory");
        __builtin_amdgcn_s_barrier();
        if (kt + 1 < k1) STAGE(cur ^ 1, kt + 1);

        const bool doB = (kt * 128 + 64) <= (qbase + 15);

        f32x4 s[8] = {};
        __builtin_amdgcn_s_setprio(1);
#pragma unroll
        for (int nt = 0; nt < 4; ++nt) {
            int row = nt * 16 + l16;
#pragma unroll
            for (int kk = 0; kk < 2; ++kk) {
                bf16x8 kf = *reinterpret_cast<const bf16x8*>(
                    (char*)k_lds[cur] + row * 128 + (((kk * 4 + g) << 4) ^ rsw));
                s[nt] = __builtin_amdgcn_mfma_f32_16x16x32_bf16(kf, qf[kk], s[nt], 0, 0, 0);
            }
        }
        if (doB) {
#pragma unroll
            for (int nt = 0; nt < 4; ++nt) {
                int row = 64 + nt * 16 + l16;
#pragma unroll
                for (int kk = 0; kk < 2; ++kk) {
                    bf16x8 kf = *reinterpret_cast<const bf16x8*>(
                        (char*)k_lds[cur] + row * 128 + (((kk * 4 + g) << 4) ^ rsw));
                    s[4 + nt] = __builtin_amdgcn_mfma_f32_16x16x32_bf16(kf, qf[kk], s[4 + nt], 0, 0, 0);
                }
            }
        }
        __builtin_amdgcn_s_setprio(0);

        if (kt * 128 + 127 > qbase) {
            int qrow = qbase + l16;
#pragma unroll
            for (int nt = 0; nt < 4; ++nt)
#pragma unroll
                for (int r = 0; r < 4; ++r) {
                    int kv = kt * 128 + nt * 16 + g * 4 + r;
                    if (kv > qrow) s[nt][r] = -1e30f;
                    if (kv + 64 > qrow) s[4 + nt][r] = -1e30f;
                }
        }

        f32x4 m4;
#pragma unroll
        for (int r = 0; r < 4; ++r) {
            float a = fmaxf(fmaxf(s[0][r], s[1][r]), fmaxf(s[2][r], s[3][r]));
            float b = fmaxf(fmaxf(s[4][r], s[5][r]), fmaxf(s[6][r], s[7][r]));
            m4[r] = fmaxf(a, b);
        }
        float mx = fmaxf(fmaxf(m4[0], m4[1]), fmaxf(m4[2], m4[3]));
        mx = fmaxf(mx, __shfl_xor(mx, 16));
        mx = fmaxf(mx, __shfl_xor(mx, 32));

        if (__any(mx > m_r + 8.0f)) {
            float mnew = fmaxf(m_r, mx);
            float alpha = __builtin_amdgcn_exp2f(m_r - mnew);
            m_r = mnew;
#pragma unroll
            for (int dt = 0; dt < 4; ++dt)
#pragma unroll
                for (int r = 0; r < 4; ++r) o_acc[dt][r] *= alpha;
            l_acc[0] *= alpha;
        }

#pragma unroll
        for (int i = 0; i < 8; ++i)
#pragma unroll
            for (int r = 0; r < 4; ++r) s[i][r] = __builtin_amdgcn_exp2f(s[i][r] - m_r);

        __builtin_amdgcn_s_setprio(1);
#pragma unroll
        for (int h64 = 0; h64 < 2; ++h64) {
            if (h64 && !doB) break;
#pragma unroll
            for (int nt = 0; nt < 4; ++nt) {
                bf16x4 pb;
#pragma unroll
                for (int r = 0; r < 4; ++r) pb[r] = (__bf16)s[h64 * 4 + nt][r];
                *reinterpret_cast<bf16x4*>(pwave + l16 * 128 + ((nt * 32 + g * 8) ^ rsw)) = pb;
            }
            bf16x8 pfrag[2];
#pragma unroll
            for (int kk = 0; kk < 2; ++kk)
                pfrag[kk] = *reinterpret_cast<const bf16x8*>(
                    pwave + l16 * 128 + (((kk * 4 + g) << 4) ^ rsw));

#pragma unroll
            for (int dt = 0; dt < 4; ++dt) {
                int row = dt * 16 + l16;
#pragma unroll
                for (int kk = 0; kk < 2; ++kk) {
                    bf16x8 vf = *reinterpret_cast<const bf16x8*>(
                        (char*)v_lds[cur][h64] + row * 128 + (((kk * 4 + g) << 4) ^ rsw));
                    o_acc[dt] = __builtin_amdgcn_mfma_f32_16x16x32_bf16(vf, pfrag[kk], o_acc[dt], 0, 0, 0);
                }
            }
            l_acc = __builtin_amdgcn_mfma_f32_16x16x32_bf16(ones, pfrag[0], l_acc, 0, 0, 0);
            l_acc = __builtin_amdgcn_mfma_f32_16x16x32_bf16(ones, pfrag[1], l_acc, 0, 0, 0);
        }
        __builtin_amdgcn_s_setprio(0);
    }

    const int ql = wave * 16 + l16;
    if (isSplit) {
        int sidx = (h * 16 + (qtile - 16)) * 2 + khalf;
        unsigned short* Op = pO + (size_t)sidx * 8192;
#pragma unroll
        for (int dt = 0; dt < 4; ++dt) {
            ushort4 ov;
            ov.x = f2bf(o_acc[dt][0]);
            ov.y = f2bf(o_acc[dt][1]);
            ov.z = f2bf(o_acc[dt][2]);
            ov.w = f2bf(o_acc[dt][3]);
            *reinterpret_cast<ushort4*>(Op + ql * 64 + dt * 16 + g * 4) = ov;
        }
        if (g == 0) {
            lmf[sidx * 256 + ql] = l_acc[0];
            lmf[sidx * 256 + 128 + ql] = m_r;
        }
    } else {
        float inv = 1.0f / l_acc[0];
        int q = qtile * 128 + ql;
#pragma unroll
        for (int dt = 0; dt < 4; ++dt) {
            ushort4 ov;
            ov.x = f2bf(o_acc[dt][0] * inv);
            ov.y = f2bf(o_acc[dt][1] * inv);
            ov.z = f2bf(o_acc[dt][2] * inv);
            ov.w = f2bf(o_acc[dt][3] * inv);
            *reinterpret_cast<ushort4*>(attnout + (size_t)q * DMODEL + h * HD + dt * 16 + g * 4) = ov;
        }
    }
}

// ---------------- merge K-half partials (qtiles 16..31) ----------------
__global__ __launch_bounds__(256) void merge_kernel(const unsigned short* __restrict__ pO,
                                                    const float* __restrict__ lmf,
                                                    unsigned short* __restrict__ attnout) {
    int idx = blockIdx.x * 256 + threadIdx.x;   // 16 h x 16 qt x 128 q x 8 d8
    if (idx >= 16 * 16 * 1024) return;
    int h = idx / (16 * 1024);
    int r = idx % (16 * 1024);
    int qt = r >> 10;
    int rr = r & 1023;
    int q = rr >> 3, d8 = rr & 7;

    int s0 = (h * 16 + qt) * 2;
    float l0 = lmf[s0 * 256 + q],       m0 = lmf[s0 * 256 + 128 + q];
    float l1 = lmf[(s0 + 1) * 256 + q], m1 = lmf[(s0 + 1) * 256 + 128 + q];
    float m = fmaxf(m0, m1);
    float a0 = __builtin_amdgcn_exp2f(m0 - m), a1 = __builtin_amdgcn_exp2f(m1 - m);
    float L = l0 * a0 + l1 * a1;
    float c0 = a0 / L, c1 = a1 / L;

    const unsigned short* O0 = pO + (size_t)s0 * 8192 + q * 64 + d8 * 8;
    const unsigned short* O1 = O0 + 8192;
    short8 v0 = *reinterpret_cast<const short8*>(O0);
    short8 v1 = *reinterpret_cast<const short8*>(O1);
    short8 o;
#pragma unroll
    for (int j = 0; j < 8; ++j) {
        float val = bf2f((unsigned short)v0[j]) * c0 + bf2f((unsigned short)v1[j]) * c1;
        o[j] = (short)f2bf(val);
    }
    int qtile = qt + 16;
    *reinterpret_cast<short8*>(attnout + (size_t)(qtile * 128 + q) * DMODEL + h * HD + d8 * 8) = o;
}

extern "C" void kernel_launch(void* const* d_in, const int* in_sizes, int n_in,
                              void* d_out, int out_size, void* d_ws, size_t ws_size,
                              hipStream_t stream) {
    const float* x = (const float*)d_in[0];
    const int* pos = (const int*)d_in[1];
    const float* wqkv = (const float*)d_in[2];
    const float* wo = (const float*)d_in[3];
    float* out = (float*)d_out;

    unsigned short* xb = (unsigned short*)d_ws;
    unsigned short* wqkvb = xb + (size_t)SEQ * DMODEL;
    unsigned short* wob = wqkvb + (size_t)NQKV * DMODEL;
    unsigned short* qkvp = wob + (size_t)DMODEL * DMODEL;
    unsigned short* vt = qkvp + (size_t)3 * HEADS * SEQ * HD;
    unsigned short* attnb = vt + (size_t)HEADS * HD * SEQ;

    // split-K scratch lives in xb/wqkvb (dead after gemm1): lmf 512KB, pO 8MB
    char* sbase = (char*)d_ws;
    float* lmf = (float*)sbase;
    unsigned short* pO = (unsigned short*)(sbase + (1 << 20));

    f2bf_all<<<2048, 256, 0, stream>>>(x, wqkv, wo, xb);

    dim3 g1(SEQ / 128, NQKV / 128);
    gemm_bt<0><<<g1, 256, 0, stream>>>(xb, wqkvb, nullptr, qkvp, SEQ, NQKV, DMODEL);

    rope_kernel<<<(2 * HEADS * SEQ * 8) / 256, 256, 0, stream>>>(qkvp, pos);
    transpose_v<<<dim3(SEQ / 64, HEADS), 256, 0, stream>>>(qkvp, vt);

    attn_kernel<<<768, 512, 0, stream>>>(qkvp, vt, attnb, pO, lmf);
    merge_kernel<<<(16 * 16 * 1024 + 255) / 256, 256, 0, stream>>>(pO, lmf, attnb);

    dim3 g2(SEQ / 128, DMODEL / 128);
    gemm_bt<1><<<g2, 256, 0, stream>>>(attnb, wob, out, nullptr, SEQ, DMODEL, DMODEL);
}